// Round 1
// baseline (1945.972 us; speedup 1.0000x reference)
//
#include <hip/hip_runtime.h>
#include <hip/hip_bf16.h>
#include <math.h>

// Problem constants
#define BB 2
#define TT 1024
#define SS 1024
#define DD 1024
#define HH 16
#define DH 64

// ---------------------------------------------------------------------------
// GEMM: Y[m,n] = sum_k X[m,k] * W[n,k] + bias[n]   (torch Linear: x @ W.T + b)
// M=2048, N=1024, K=1024. 64x64 tile, BK=16, 256 threads, 4x4 micro-tile.
// ---------------------------------------------------------------------------
#define GT 64
#define GBK 16

__global__ __launch_bounds__(256) void gemm_xwt(
    const float* __restrict__ X, const float* __restrict__ W,
    const float* __restrict__ bias, float* __restrict__ Y,
    int M, int N, int K)
{
    __shared__ float Xs[GBK][GT];
    __shared__ float Ws[GBK][GT];

    const int bm = blockIdx.y * GT;
    const int bn = blockIdx.x * GT;
    const int tid = threadIdx.x;

    const int tm = (tid >> 4) * 4;   // 0..60
    const int tn = (tid & 15) * 4;   // 0..60

    // loader mapping: each thread loads one float4 along K
    const int lm = tid >> 2;          // 0..63
    const int lk = (tid & 3) * 4;     // 0,4,8,12

    float acc[4][4] = {};

    for (int k0 = 0; k0 < K; k0 += GBK) {
        float4 xv = *(const float4*)&X[(size_t)(bm + lm) * K + k0 + lk];
        float4 wv = *(const float4*)&W[(size_t)(bn + lm) * K + k0 + lk];
        Xs[lk + 0][lm] = xv.x; Xs[lk + 1][lm] = xv.y;
        Xs[lk + 2][lm] = xv.z; Xs[lk + 3][lm] = xv.w;
        Ws[lk + 0][lm] = wv.x; Ws[lk + 1][lm] = wv.y;
        Ws[lk + 2][lm] = wv.z; Ws[lk + 3][lm] = wv.w;
        __syncthreads();

        #pragma unroll
        for (int kk = 0; kk < GBK; kk++) {
            float a0 = Xs[kk][tm + 0], a1 = Xs[kk][tm + 1];
            float a2 = Xs[kk][tm + 2], a3 = Xs[kk][tm + 3];
            float b0 = Ws[kk][tn + 0], b1 = Ws[kk][tn + 1];
            float b2 = Ws[kk][tn + 2], b3 = Ws[kk][tn + 3];
            acc[0][0] += a0 * b0; acc[0][1] += a0 * b1; acc[0][2] += a0 * b2; acc[0][3] += a0 * b3;
            acc[1][0] += a1 * b0; acc[1][1] += a1 * b1; acc[1][2] += a1 * b2; acc[1][3] += a1 * b3;
            acc[2][0] += a2 * b0; acc[2][1] += a2 * b1; acc[2][2] += a2 * b2; acc[2][3] += a2 * b3;
            acc[3][0] += a3 * b0; acc[3][1] += a3 * b1; acc[3][2] += a3 * b2; acc[3][3] += a3 * b3;
        }
        __syncthreads();
    }

    #pragma unroll
    for (int i = 0; i < 4; i++) {
        #pragma unroll
        for (int j = 0; j < 4; j++) {
            Y[(size_t)(bm + tm + i) * N + bn + tn + j] = acc[i][j] + bias[bn + tn + j];
        }
    }
}

// ---------------------------------------------------------------------------
// Attention: one block per (b,h,t). 256 threads.
//  scores -> clip -> causal mask -> softmax -> mult bias scale -> renorm
//  -> write attn row -> out_h[t,:] = attn . V
// ---------------------------------------------------------------------------
__global__ __launch_bounds__(256) void attn_kernel(
    const float* __restrict__ qh, const float* __restrict__ kh,
    const float* __restrict__ vh, const float* __restrict__ attn_bias,
    const float* __restrict__ bias_scale_p,
    float* __restrict__ attn_out, float* __restrict__ attn_w)
{
    const int bid = blockIdx.x;
    const int t = bid & (TT - 1);
    const int h = (bid >> 10) & (HH - 1);
    const int b = bid >> 14;
    const int tid = threadIdx.x;

    __shared__ float qrow[DH];
    __shared__ float sc[SS];
    __shared__ float red[256];
    __shared__ float partial[4][DH];

    const float* qptr = qh + (((size_t)b * TT + t) * HH + h) * DH;
    if (tid < DH) qrow[tid] = qptr[tid];
    __syncthreads();

    const float bscale = bias_scale_p[0];

    // ---- scores: sc[s] = clip(q.k/8), masked -> -inf ----
    const float* kbase = kh + ((size_t)b * SS * HH + h) * DH;
    float lmax = -INFINITY;
    for (int s = tid; s < SS; s += 256) {
        const float4* kr = (const float4*)(kbase + (size_t)s * HH * DH);
        float dot = 0.f;
        #pragma unroll
        for (int i = 0; i < 16; i++) {
            float4 kv = kr[i];
            dot += qrow[4 * i + 0] * kv.x + qrow[4 * i + 1] * kv.y
                 + qrow[4 * i + 2] * kv.z + qrow[4 * i + 3] * kv.w;
        }
        dot *= 0.125f;                                   // 1/sqrt(DH)
        dot = fminf(fmaxf(dot, -80.f), 80.f);
        if (s > t) dot = -INFINITY;
        sc[s] = dot;
        lmax = fmaxf(lmax, dot);
    }
    red[tid] = lmax;
    __syncthreads();
    for (int off = 128; off > 0; off >>= 1) {
        if (tid < off) red[tid] = fmaxf(red[tid], red[tid + off]);
        __syncthreads();
    }
    const float m = red[0];
    __syncthreads();

    // ---- exp & softmax denom ----
    float lsum = 0.f;
    for (int s = tid; s < SS; s += 256) {
        float p = (s <= t) ? __expf(sc[s] - m) : 0.f;
        sc[s] = p;
        lsum += p;
    }
    red[tid] = lsum;
    __syncthreads();
    for (int off = 128; off > 0; off >>= 1) {
        if (tid < off) red[tid] += red[tid + off];
        __syncthreads();
    }
    const float inv = 1.f / red[0];
    __syncthreads();

    // ---- multiplicative bias scale + second denom ----
    const float* brow = attn_bias + (((size_t)b * HH + h) * TT + t) * SS;
    float lsum2 = 0.f;
    for (int s = tid; s < SS; s += 256) {
        float a = sc[s] * inv;
        float x = brow[s];
        // tanh(x) = sign(x) * (1 - e^{-2|x|}) / (1 + e^{-2|x|})   (overflow-safe)
        float e = __expf(-2.f * fabsf(x));
        float th = (1.f - e) / (1.f + e);
        th = copysignf(th, x);
        float scl = fmaxf(1.f + bscale * th, 1e-9f);
        float w = a * scl;
        sc[s] = w;
        lsum2 += w;
    }
    red[tid] = lsum2;
    __syncthreads();
    for (int off = 128; off > 0; off >>= 1) {
        if (tid < off) red[tid] += red[tid + off];
        __syncthreads();
    }
    const float inv2 = 1.f / (red[0] + 1e-9f);
    __syncthreads();

    // ---- finalize + write attn row ----
    float* arow = attn_w + (((size_t)b * HH + h) * TT + t) * SS;
    for (int s = tid; s < SS; s += 256) {
        float w = sc[s] * inv2;
        sc[s] = w;
        arow[s] = w;
    }
    __syncthreads();

    // ---- out_h = attn . V  (4 groups of 64 lanes over s; dh = lane) ----
    const int g = tid >> 6;
    const int dh = tid & 63;
    const float* vbase = vh + ((size_t)b * SS * HH + h) * DH + dh;
    float acc = 0.f;
    for (int s = g; s <= t; s += 4) {
        acc += sc[s] * vbase[(size_t)s * HH * DH];
    }
    partial[g][dh] = acc;
    __syncthreads();
    if (tid < DH) {
        float o = partial[0][tid] + partial[1][tid] + partial[2][tid] + partial[3][tid];
        attn_out[(((size_t)b * TT + t) * HH + h) * DH + tid] = o;
    }
}

// ---------------------------------------------------------------------------
extern "C" void kernel_launch(void* const* d_in, const int* in_sizes, int n_in,
                              void* d_out, int out_size, void* d_ws, size_t ws_size,
                              hipStream_t stream)
{
    const float* q   = (const float*)d_in[0];
    const float* k   = (const float*)d_in[1];
    const float* v   = (const float*)d_in[2];
    // d_in[3] = attn_mask (causal, computed analytically — unused)
    const float* attn_bias = (const float*)d_in[4];
    const float* Wq = (const float*)d_in[5];
    const float* bq = (const float*)d_in[6];
    const float* Wk = (const float*)d_in[7];
    const float* bk = (const float*)d_in[8];
    const float* Wv = (const float*)d_in[9];
    const float* bv = (const float*)d_in[10];
    const float* Wo = (const float*)d_in[11];
    const float* bo = (const float*)d_in[12];
    const float* bscale = (const float*)d_in[13];

    const int M = BB * TT;   // 2048
    float* ws = (float*)d_ws;
    float* qh = ws;                        // 2048*1024
    float* kh = qh + (size_t)M * DD;
    float* vh = kh + (size_t)M * DD;
    float* ao = vh + (size_t)M * DD;       // attention output (B,T,D)

    float* out  = (float*)d_out;                       // (B,T,D)
    float* attn = out + (size_t)BB * TT * DD;          // (B,H,T,S)

    dim3 gblock(256);
    dim3 ggrid(DD / GT, M / GT);           // (16, 32)

    gemm_xwt<<<ggrid, gblock, 0, stream>>>(q, Wq, bq, qh, M, DD, DD);
    gemm_xwt<<<ggrid, gblock, 0, stream>>>(k, Wk, bk, kh, M, DD, DD);
    gemm_xwt<<<ggrid, gblock, 0, stream>>>(v, Wv, bv, vh, M, DD, DD);

    attn_kernel<<<BB * HH * TT, 256, 0, stream>>>(qh, kh, vh, attn_bias, bscale, ao, attn);

    gemm_xwt<<<ggrid, gblock, 0, stream>>>(ao, Wo, bo, out, M, DD, DD);
}

// Round 2
// 815.028 us; speedup vs baseline: 2.3876x; 2.3876x over previous
//
#include <hip/hip_runtime.h>
#include <hip/hip_bf16.h>
#include <math.h>

// Problem constants
#define BB 2
#define TT 1024
#define SS 1024
#define DD 1024
#define HH 16
#define DH 64

// ---------------------------------------------------------------------------
// GEMM: Y[m,n] = sum_k X[m,k] * W[n,k] + bias[n]   (torch Linear: x @ W.T + b)
// M=2048, N=1024, K=1024. 64x64 tile, BK=16, 256 threads, 4x4 micro-tile.
// ---------------------------------------------------------------------------
#define GT 64
#define GBK 16

__global__ __launch_bounds__(256) void gemm_xwt(
    const float* __restrict__ X, const float* __restrict__ W,
    const float* __restrict__ bias, float* __restrict__ Y,
    int M, int N, int K)
{
    __shared__ float Xs[GBK][GT];
    __shared__ float Ws[GBK][GT];

    const int bm = blockIdx.y * GT;
    const int bn = blockIdx.x * GT;
    const int tid = threadIdx.x;

    const int tm = (tid >> 4) * 4;   // 0..60
    const int tn = (tid & 15) * 4;   // 0..60

    const int lm = tid >> 2;          // 0..63
    const int lk = (tid & 3) * 4;     // 0,4,8,12

    float acc[4][4] = {};

    for (int k0 = 0; k0 < K; k0 += GBK) {
        float4 xv = *(const float4*)&X[(size_t)(bm + lm) * K + k0 + lk];
        float4 wv = *(const float4*)&W[(size_t)(bn + lm) * K + k0 + lk];
        Xs[lk + 0][lm] = xv.x; Xs[lk + 1][lm] = xv.y;
        Xs[lk + 2][lm] = xv.z; Xs[lk + 3][lm] = xv.w;
        Ws[lk + 0][lm] = wv.x; Ws[lk + 1][lm] = wv.y;
        Ws[lk + 2][lm] = wv.z; Ws[lk + 3][lm] = wv.w;
        __syncthreads();

        #pragma unroll
        for (int kk = 0; kk < GBK; kk++) {
            float a0 = Xs[kk][tm + 0], a1 = Xs[kk][tm + 1];
            float a2 = Xs[kk][tm + 2], a3 = Xs[kk][tm + 3];
            float b0 = Ws[kk][tn + 0], b1 = Ws[kk][tn + 1];
            float b2 = Ws[kk][tn + 2], b3 = Ws[kk][tn + 3];
            acc[0][0] += a0 * b0; acc[0][1] += a0 * b1; acc[0][2] += a0 * b2; acc[0][3] += a0 * b3;
            acc[1][0] += a1 * b0; acc[1][1] += a1 * b1; acc[1][2] += a1 * b2; acc[1][3] += a1 * b3;
            acc[2][0] += a2 * b0; acc[2][1] += a2 * b1; acc[2][2] += a2 * b2; acc[2][3] += a2 * b3;
            acc[3][0] += a3 * b0; acc[3][1] += a3 * b1; acc[3][2] += a3 * b2; acc[3][3] += a3 * b3;
        }
        __syncthreads();
    }

    #pragma unroll
    for (int i = 0; i < 4; i++) {
        #pragma unroll
        for (int j = 0; j < 4; j++) {
            Y[(size_t)(bm + tm + i) * N + bn + tn + j] = acc[i][j] + bias[bn + tn + j];
        }
    }
}

// ---------------------------------------------------------------------------
// scores_kernel: attn_raw[b,h,t,s] = clip(qh[b,t,h,:].kh[b,s,h,:] / 8, +-80)
// One block = one 64x64 (t,s) tile for one (b,h). Causal: skip si > ti.
// Writes raw scores IN-PLACE into the attn output region.
// ---------------------------------------------------------------------------
__global__ __launch_bounds__(256) void scores_kernel(
    const float* __restrict__ qh, const float* __restrict__ kh,
    float* __restrict__ attn)
{
    const int si = blockIdx.x;      // s-tile
    const int ti = blockIdx.y;      // t-tile
    const int bh = blockIdx.z;      // b*H + h
    if (si > ti) return;
    const int b = bh >> 4, h = bh & 15;

    __shared__ float Qs[64][64];    // [k][t]
    __shared__ float Ks[64][64];    // [k][s]

    const int tid = threadIdx.x;
    {
        const int r0 = tid >> 4;         // 0..15
        const int c4 = (tid & 15) * 4;   // 0..60
        #pragma unroll
        for (int jj = 0; jj < 4; jj++) {
            int r = r0 + jj * 16;
            float4 qv = *(const float4*)&qh[(((size_t)b * TT + ti * 64 + r) * HH + h) * DH + c4];
            float4 kv = *(const float4*)&kh[(((size_t)b * SS + si * 64 + r) * HH + h) * DH + c4];
            Qs[c4 + 0][r] = qv.x; Qs[c4 + 1][r] = qv.y;
            Qs[c4 + 2][r] = qv.z; Qs[c4 + 3][r] = qv.w;
            Ks[c4 + 0][r] = kv.x; Ks[c4 + 1][r] = kv.y;
            Ks[c4 + 2][r] = kv.z; Ks[c4 + 3][r] = kv.w;
        }
    }
    __syncthreads();

    const int tm = (tid >> 4) * 4;
    const int tn = (tid & 15) * 4;
    float acc[4][4] = {};

    #pragma unroll 16
    for (int kk = 0; kk < 64; kk++) {
        float a0 = Qs[kk][tm + 0], a1 = Qs[kk][tm + 1];
        float a2 = Qs[kk][tm + 2], a3 = Qs[kk][tm + 3];
        float b0 = Ks[kk][tn + 0], b1 = Ks[kk][tn + 1];
        float b2 = Ks[kk][tn + 2], b3 = Ks[kk][tn + 3];
        acc[0][0] += a0 * b0; acc[0][1] += a0 * b1; acc[0][2] += a0 * b2; acc[0][3] += a0 * b3;
        acc[1][0] += a1 * b0; acc[1][1] += a1 * b1; acc[1][2] += a1 * b2; acc[1][3] += a1 * b3;
        acc[2][0] += a2 * b0; acc[2][1] += a2 * b1; acc[2][2] += a2 * b2; acc[2][3] += a2 * b3;
        acc[3][0] += a3 * b0; acc[3][1] += a3 * b1; acc[3][2] += a3 * b2; acc[3][3] += a3 * b3;
    }

    #pragma unroll
    for (int i = 0; i < 4; i++) {
        float4 o;
        o.x = fminf(fmaxf(acc[i][0] * 0.125f, -80.f), 80.f);
        o.y = fminf(fmaxf(acc[i][1] * 0.125f, -80.f), 80.f);
        o.z = fminf(fmaxf(acc[i][2] * 0.125f, -80.f), 80.f);
        o.w = fminf(fmaxf(acc[i][3] * 0.125f, -80.f), 80.f);
        *(float4*)&attn[((size_t)bh * TT + ti * 64 + tm + i) * SS + si * 64 + tn] = o;
    }
}

// ---------------------------------------------------------------------------
// softmax_bias_kernel: per-row softmax over s<=t, multiplicative tanh bias,
// renormalize, write final attn (zeros for s>t). Register-resident:
// thread tid owns s = 4*tid .. 4*tid+3.
// ---------------------------------------------------------------------------
__global__ __launch_bounds__(256) void softmax_bias_kernel(
    const float* __restrict__ attn_bias, const float* __restrict__ bias_scale_p,
    float* __restrict__ attn)
{
    const int bid = blockIdx.x;         // bh*T + t
    const int t = bid & (TT - 1);
    const int tid = threadIdx.x;
    const int s0 = tid * 4;

    float* row = attn + (size_t)bid * SS;
    const float* brow = attn_bias + (size_t)bid * SS;

    __shared__ float red[256];

    // load + mask
    float v0 = -INFINITY, v1 = -INFINITY, v2 = -INFINITY, v3 = -INFINITY;
    if (s0 <= t) {
        float4 rv = *(const float4*)&row[s0];
        v0 = rv.x;
        v1 = (s0 + 1 <= t) ? rv.y : -INFINITY;
        v2 = (s0 + 2 <= t) ? rv.z : -INFINITY;
        v3 = (s0 + 3 <= t) ? rv.w : -INFINITY;
    }
    float lmax = fmaxf(fmaxf(v0, v1), fmaxf(v2, v3));
    red[tid] = lmax;
    __syncthreads();
    for (int off = 128; off > 0; off >>= 1) {
        if (tid < off) red[tid] = fmaxf(red[tid], red[tid + off]);
        __syncthreads();
    }
    const float m = red[0];
    __syncthreads();

    float p0 = (v0 > -INFINITY) ? __expf(v0 - m) : 0.f;
    float p1 = (v1 > -INFINITY) ? __expf(v1 - m) : 0.f;
    float p2 = (v2 > -INFINITY) ? __expf(v2 - m) : 0.f;
    float p3 = (v3 > -INFINITY) ? __expf(v3 - m) : 0.f;
    red[tid] = p0 + p1 + p2 + p3;
    __syncthreads();
    for (int off = 128; off > 0; off >>= 1) {
        if (tid < off) red[tid] += red[tid + off];
        __syncthreads();
    }
    const float inv = 1.f / red[0];
    __syncthreads();

    const float bscale = bias_scale_p[0];
    float w0 = 0.f, w1 = 0.f, w2 = 0.f, w3 = 0.f;
    if (s0 <= t) {
        float4 bv = *(const float4*)&brow[s0];
        // overflow-safe tanh
        float e0 = __expf(-2.f * fabsf(bv.x));
        float e1 = __expf(-2.f * fabsf(bv.y));
        float e2 = __expf(-2.f * fabsf(bv.z));
        float e3 = __expf(-2.f * fabsf(bv.w));
        float t0 = copysignf((1.f - e0) / (1.f + e0), bv.x);
        float t1 = copysignf((1.f - e1) / (1.f + e1), bv.y);
        float t2 = copysignf((1.f - e2) / (1.f + e2), bv.z);
        float t3 = copysignf((1.f - e3) / (1.f + e3), bv.w);
        w0 = p0 * inv * fmaxf(1.f + bscale * t0, 1e-9f);
        w1 = p1 * inv * fmaxf(1.f + bscale * t1, 1e-9f);
        w2 = p2 * inv * fmaxf(1.f + bscale * t2, 1e-9f);
        w3 = p3 * inv * fmaxf(1.f + bscale * t3, 1e-9f);
    }
    red[tid] = w0 + w1 + w2 + w3;
    __syncthreads();
    for (int off = 128; off > 0; off >>= 1) {
        if (tid < off) red[tid] += red[tid + off];
        __syncthreads();
    }
    const float inv2 = 1.f / (red[0] + 1e-9f);

    float4 o;
    o.x = w0 * inv2; o.y = w1 * inv2; o.z = w2 * inv2; o.w = w3 * inv2;
    *(float4*)&row[s0] = o;
}

// ---------------------------------------------------------------------------
// av_kernel: ao[b,t,h,dh] = sum_s attn[b,h,t,s] * vh[b,s,h,dh]
// One block = 32 t-rows x 64 dh for one (b,h); loop s-tiles of 64 (causal skip).
// attn has exact zeros for s>t, so no masking needed.
// ---------------------------------------------------------------------------
__global__ __launch_bounds__(256) void av_kernel(
    const float* __restrict__ attn, const float* __restrict__ vh,
    float* __restrict__ ao)
{
    const int tb = blockIdx.x;      // 0..31 (32-row t-tiles)
    const int bh = blockIdx.y;      // b*H + h
    const int b = bh >> 4, h = bh & 15;
    const int t0 = tb * 32;
    const int n_st = (t0 + 31) / 64 + 1;

    __shared__ float As[32][64];    // [t][s]
    __shared__ float Vs[64][64];    // [s][dh]

    const int tid = threadIdx.x;
    const int tm = (tid >> 5) * 4;  // 0..28
    const int tn = (tid & 31) * 2;  // 0..62
    float acc[4][2] = {};

    const int r0 = tid >> 4;            // 0..15
    const int c4 = (tid & 15) * 4;      // 0..60

    for (int st = 0; st < n_st; st++) {
        const int s0 = st * 64;
        #pragma unroll
        for (int jj = 0; jj < 2; jj++) {
            int r = r0 + jj * 16;
            *(float4*)&As[r][c4] =
                *(const float4*)&attn[((size_t)bh * TT + t0 + r) * SS + s0 + c4];
        }
        #pragma unroll
        for (int jj = 0; jj < 4; jj++) {
            int r = r0 + jj * 16;
            *(float4*)&Vs[r][c4] =
                *(const float4*)&vh[(((size_t)b * SS + s0 + r) * HH + h) * DH + c4];
        }
        __syncthreads();

        #pragma unroll 16
        for (int ss = 0; ss < 64; ss++) {
            float a0 = As[tm + 0][ss], a1 = As[tm + 1][ss];
            float a2 = As[tm + 2][ss], a3 = As[tm + 3][ss];
            float b0 = Vs[ss][tn + 0], b1 = Vs[ss][tn + 1];
            acc[0][0] += a0 * b0; acc[0][1] += a0 * b1;
            acc[1][0] += a1 * b0; acc[1][1] += a1 * b1;
            acc[2][0] += a2 * b0; acc[2][1] += a2 * b1;
            acc[3][0] += a3 * b0; acc[3][1] += a3 * b1;
        }
        __syncthreads();
    }

    #pragma unroll
    for (int i = 0; i < 4; i++) {
        #pragma unroll
        for (int j = 0; j < 2; j++) {
            ao[(((size_t)b * TT + t0 + tm + i) * HH + h) * DH + tn + j] = acc[i][j];
        }
    }
}

// ---------------------------------------------------------------------------
extern "C" void kernel_launch(void* const* d_in, const int* in_sizes, int n_in,
                              void* d_out, int out_size, void* d_ws, size_t ws_size,
                              hipStream_t stream)
{
    const float* q   = (const float*)d_in[0];
    const float* k   = (const float*)d_in[1];
    const float* v   = (const float*)d_in[2];
    // d_in[3] = attn_mask (causal, computed analytically — unused)
    const float* attn_bias = (const float*)d_in[4];
    const float* Wq = (const float*)d_in[5];
    const float* bq = (const float*)d_in[6];
    const float* Wk = (const float*)d_in[7];
    const float* bk = (const float*)d_in[8];
    const float* Wv = (const float*)d_in[9];
    const float* bv = (const float*)d_in[10];
    const float* Wo = (const float*)d_in[11];
    const float* bo = (const float*)d_in[12];
    const float* bscale = (const float*)d_in[13];

    const int M = BB * TT;   // 2048
    float* ws = (float*)d_ws;
    float* qh = ws;                        // (B,T,H,DH)
    float* kh = qh + (size_t)M * DD;       // (B,S,H,DH)
    float* vh = kh + (size_t)M * DD;       // (B,S,H,DH)
    float* ao = vh + (size_t)M * DD;       // (B,T,H,DH)

    float* out  = (float*)d_out;                       // (B,T,D)
    float* attn = out + (size_t)BB * TT * DD;          // (B,H,T,S)

    dim3 gblock(256);
    dim3 ggrid(DD / GT, M / GT);           // (16, 32)

    gemm_xwt<<<ggrid, gblock, 0, stream>>>(q, Wq, bq, qh, M, DD, DD);
    gemm_xwt<<<ggrid, gblock, 0, stream>>>(k, Wk, bk, kh, M, DD, DD);
    gemm_xwt<<<ggrid, gblock, 0, stream>>>(v, Wv, bv, vh, M, DD, DD);

    scores_kernel<<<dim3(16, 16, 32), gblock, 0, stream>>>(qh, kh, attn);
    softmax_bias_kernel<<<dim3(BB * HH * TT), gblock, 0, stream>>>(attn_bias, bscale, attn);
    av_kernel<<<dim3(32, 32), gblock, 0, stream>>>(attn, vh, ao);

    gemm_xwt<<<ggrid, gblock, 0, stream>>>(ao, Wo, bo, out, M, DD, DD);
}

// Round 3
// 390.101 us; speedup vs baseline: 4.9884x; 2.0893x over previous
//
#include <hip/hip_runtime.h>
#include <hip/hip_bf16.h>
#include <math.h>

#define BB 2
#define TT 1024
#define SS 1024
#define DD 1024
#define HH 16
#define DH 64

typedef __attribute__((ext_vector_type(8))) short bf16x8;
typedef __attribute__((ext_vector_type(4))) float f32x4;
typedef unsigned short ushort_t;

#define AS3(p) ((__attribute__((address_space(3))) unsigned int*)(p))
#define AS1(p) ((const __attribute__((address_space(1))) unsigned int*)(p))

__device__ __forceinline__ unsigned short f2b(float f) {
    union { float f; unsigned u; } x; x.f = f;
    unsigned r = x.u + 0x7FFFu + ((x.u >> 16) & 1u);
    return (unsigned short)(r >> 16);
}

// ---------------------------------------------------------------------------
// fp32 -> bf16 conversion kernels
// ---------------------------------------------------------------------------
__global__ __launch_bounds__(256) void cvt3_kernel(
    const float* __restrict__ a, const float* __restrict__ b, const float* __restrict__ c,
    ushort_t* __restrict__ oa, ushort_t* __restrict__ ob, ushort_t* __restrict__ oc)
{
    const float* src = (blockIdx.y == 0) ? a : (blockIdx.y == 1) ? b : c;
    ushort_t* dst    = (blockIdx.y == 0) ? oa : (blockIdx.y == 1) ? ob : oc;
    size_t i = ((size_t)blockIdx.x * 256 + threadIdx.x) * 8;
    float4 v0 = *(const float4*)&src[i];
    float4 v1 = *(const float4*)&src[i + 4];
    uint4 o;
    o.x = f2b(v0.x) | ((unsigned)f2b(v0.y) << 16);
    o.y = f2b(v0.z) | ((unsigned)f2b(v0.w) << 16);
    o.z = f2b(v1.x) | ((unsigned)f2b(v1.y) << 16);
    o.w = f2b(v1.z) | ((unsigned)f2b(v1.w) << 16);
    *(uint4*)&dst[i] = o;
}

__global__ __launch_bounds__(256) void cvt4_kernel(
    const float* __restrict__ a, const float* __restrict__ b,
    const float* __restrict__ c, const float* __restrict__ d,
    ushort_t* __restrict__ oa, ushort_t* __restrict__ ob,
    ushort_t* __restrict__ oc, ushort_t* __restrict__ od)
{
    const float* src = (blockIdx.y == 0) ? a : (blockIdx.y == 1) ? b : (blockIdx.y == 2) ? c : d;
    ushort_t* dst    = (blockIdx.y == 0) ? oa : (blockIdx.y == 1) ? ob : (blockIdx.y == 2) ? oc : od;
    size_t i = ((size_t)blockIdx.x * 256 + threadIdx.x) * 8;
    float4 v0 = *(const float4*)&src[i];
    float4 v1 = *(const float4*)&src[i + 4];
    uint4 o;
    o.x = f2b(v0.x) | ((unsigned)f2b(v0.y) << 16);
    o.y = f2b(v0.z) | ((unsigned)f2b(v0.w) << 16);
    o.z = f2b(v1.x) | ((unsigned)f2b(v1.y) << 16);
    o.w = f2b(v1.z) | ((unsigned)f2b(v1.w) << 16);
    *(uint4*)&dst[i] = o;
}

// ---------------------------------------------------------------------------
// 128x128 bf16 MFMA GEMM mainloop: D = A (MxK) . Bw^T (N x K), both K-contig.
// BK=32, global_load_lds width-16 staging, XOR chunk swizzle (2-way max).
// ---------------------------------------------------------------------------
__device__ __forceinline__ void gemm128_mainloop(
    const ushort_t* __restrict__ A,   // pre-offset to (bm,0), row stride K
    const ushort_t* __restrict__ Bw,  // pre-offset to (bn,0), row stride K
    int K, ushort_t* Asm, ushort_t* Bsm, f32x4 acc[4][4])
{
    const int tid = threadIdx.x;
    const int wave = tid >> 6, lane = tid & 63;
    const int sr = lane >> 2;                        // row within 16-row group
    const int gc = (lane & 3) ^ ((lane >> 3) & 3);   // swizzled global chunk
    const int l15 = lane & 15, q = lane >> 4;
    const int mblk = (wave >> 1) * 64, nblk = (wave & 1) * 64;

    for (int k0 = 0; k0 < K; k0 += 32) {
        #pragma unroll
        for (int o = 0; o < 2; o++) {
            int r0 = (wave * 2 + o) * 16;
            __builtin_amdgcn_global_load_lds(AS1(A + (size_t)(r0 + sr) * K + k0 + gc * 8),
                                             AS3(Asm + r0 * 32), 16, 0, 0);
            __builtin_amdgcn_global_load_lds(AS1(Bw + (size_t)(r0 + sr) * K + k0 + gc * 8),
                                             AS3(Bsm + r0 * 32), 16, 0, 0);
        }
        __syncthreads();

        bf16x8 av[4], bv[4];
        #pragma unroll
        for (int mi = 0; mi < 4; mi++) {
            int r = mblk + mi * 16 + l15;
            av[mi] = *(const bf16x8*)&Asm[r * 32 + (q ^ ((r >> 1) & 3)) * 8];
        }
        #pragma unroll
        for (int ni = 0; ni < 4; ni++) {
            int r = nblk + ni * 16 + l15;
            bv[ni] = *(const bf16x8*)&Bsm[r * 32 + (q ^ ((r >> 1) & 3)) * 8];
        }
        #pragma unroll
        for (int mi = 0; mi < 4; mi++)
            #pragma unroll
            for (int ni = 0; ni < 4; ni++)
                acc[mi][ni] = __builtin_amdgcn_mfma_f32_16x16x32_bf16(av[mi], bv[ni], acc[mi][ni], 0, 0, 0);
        __syncthreads();
    }
}

// Fused Q/K/V projections: z picks which. Output bf16 (B,T,D).
__global__ __launch_bounds__(256) void proj_gemm(
    const ushort_t* __restrict__ qb, const ushort_t* __restrict__ kb, const ushort_t* __restrict__ vb,
    const ushort_t* __restrict__ Wqb, const ushort_t* __restrict__ Wkb, const ushort_t* __restrict__ Wvb,
    const float* __restrict__ bq, const float* __restrict__ bk, const float* __restrict__ bv,
    ushort_t* __restrict__ qh, ushort_t* __restrict__ kh, ushort_t* __restrict__ vh)
{
    __shared__ ushort_t Asm[128 * 32];
    __shared__ ushort_t Bsm[128 * 32];
    const int z = blockIdx.z;
    const ushort_t* A = (z == 0) ? qb : (z == 1) ? kb : vb;
    const ushort_t* W = (z == 0) ? Wqb : (z == 1) ? Wkb : Wvb;
    const float* bias = (z == 0) ? bq : (z == 1) ? bk : bv;
    ushort_t* Y = (z == 0) ? qh : (z == 1) ? kh : vh;

    const int bm = blockIdx.y * 128, bn = blockIdx.x * 128;
    f32x4 acc[4][4];
    #pragma unroll
    for (int i = 0; i < 4; i++)
        #pragma unroll
        for (int j = 0; j < 4; j++) acc[i][j] = (f32x4)(0.f);

    gemm128_mainloop(A + (size_t)bm * DD, W + (size_t)bn * DD, DD, Asm, Bsm, acc);

    const int lane = threadIdx.x & 63, wave = threadIdx.x >> 6;
    const int mblk = (wave >> 1) * 64, nblk = (wave & 1) * 64;
    const int l15 = lane & 15, q = lane >> 4;
    #pragma unroll
    for (int mi = 0; mi < 4; mi++) {
        #pragma unroll
        for (int ni = 0; ni < 4; ni++) {
            int col = bn + nblk + ni * 16 + l15;
            float bcol = bias[col];
            #pragma unroll
            for (int r = 0; r < 4; r++) {
                int row = bm + mblk + mi * 16 + q * 4 + r;
                Y[(size_t)row * DD + col] = f2b(acc[mi][ni][r] + bcol);
            }
        }
    }
}

// Output projection: bf16 in, fp32 out + bias.
__global__ __launch_bounds__(256) void oproj_gemm(
    const ushort_t* __restrict__ A, const ushort_t* __restrict__ W,
    const float* __restrict__ bias, float* __restrict__ Y)
{
    __shared__ ushort_t Asm[128 * 32];
    __shared__ ushort_t Bsm[128 * 32];
    const int bm = blockIdx.y * 128, bn = blockIdx.x * 128;
    f32x4 acc[4][4];
    #pragma unroll
    for (int i = 0; i < 4; i++)
        #pragma unroll
        for (int j = 0; j < 4; j++) acc[i][j] = (f32x4)(0.f);

    gemm128_mainloop(A + (size_t)bm * DD, W + (size_t)bn * DD, DD, Asm, Bsm, acc);

    const int lane = threadIdx.x & 63, wave = threadIdx.x >> 6;
    const int mblk = (wave >> 1) * 64, nblk = (wave & 1) * 64;
    const int l15 = lane & 15, q = lane >> 4;
    #pragma unroll
    for (int mi = 0; mi < 4; mi++) {
        #pragma unroll
        for (int ni = 0; ni < 4; ni++) {
            int col = bn + nblk + ni * 16 + l15;
            float bcol = bias[col];
            #pragma unroll
            for (int r = 0; r < 4; r++) {
                int row = bm + mblk + mi * 16 + q * 4 + r;
                Y[(size_t)row * DD + col] = acc[mi][ni][r] + bcol;
            }
        }
    }
}

// ---------------------------------------------------------------------------
// V transpose: vh (B,S,H,DH) bf16 -> vT (B,H,DH,S) bf16
// ---------------------------------------------------------------------------
__global__ __launch_bounds__(256) void transpose_v(
    const ushort_t* __restrict__ vh, ushort_t* __restrict__ vT)
{
    __shared__ ushort_t Ls[64][72];
    const int s0 = blockIdx.x * 64;
    const int bh = blockIdx.y;
    const int b = bh >> 4, h = bh & 15;
    const int tid = threadIdx.x;
    const int r = tid >> 2, c16 = (tid & 3) * 16;

    const ushort_t* src = &vh[((size_t)(b * SS + s0 + r) * HH + h) * DH + c16];
    uint4 u0 = *(const uint4*)src;
    uint4 u1 = *(const uint4*)(src + 8);
    ushort_t tmp[16];
    *(uint4*)&tmp[0] = u0; *(uint4*)&tmp[8] = u1;
    #pragma unroll
    for (int j = 0; j < 16; j++) Ls[c16 + j][r] = tmp[j];
    __syncthreads();

    const int dh = r;
    uint4 w0 = *(const uint4*)&Ls[dh][c16];
    uint4 w1 = *(const uint4*)&Ls[dh][c16 + 8];
    ushort_t* dst = &vT[((size_t)bh * DH + dh) * SS + s0 + c16];
    *(uint4*)dst = w0;
    *(uint4*)(dst + 8) = w1;
}

// ---------------------------------------------------------------------------
// scores: attn_raw[bh,t,s] = clip(qh.kh/8). 128x128 tile per block, causal
// tiles only. K=64 (one-shot staging, 2 MFMA k-steps).
// ---------------------------------------------------------------------------
__global__ __launch_bounds__(256) void scores_mfma(
    const ushort_t* __restrict__ qh, const ushort_t* __restrict__ kh,
    float* __restrict__ attn)
{
    __shared__ ushort_t Qs[128 * 64];
    __shared__ ushort_t Ks[128 * 64];

    int idx = blockIdx.x, ti = 0;
    while (idx >= ti + 1) { idx -= ti + 1; ti++; }
    const int si = idx;
    const int bh = blockIdx.y;
    const int b = bh >> 4, h = bh & 15;
    const int t0 = ti * 128, s0 = si * 128;

    const int tid = threadIdx.x;
    const int wave = tid >> 6, lane = tid & 63;
    const int sr8 = lane >> 3;                 // 0..7: row within 8-row group
    const int gc8 = (lane & 7) ^ sr8;          // swizzled chunk (8 x 16B per row)

    #pragma unroll
    for (int o = 0; o < 4; o++) {
        int r0 = (wave * 4 + o) * 8;
        int r = r0 + sr8;
        __builtin_amdgcn_global_load_lds(
            AS1(qh + ((size_t)(b * TT + t0 + r) * HH + h) * DH + gc8 * 8),
            AS3(Qs + r0 * 64), 16, 0, 0);
        __builtin_amdgcn_global_load_lds(
            AS1(kh + ((size_t)(b * SS + s0 + r) * HH + h) * DH + gc8 * 8),
            AS3(Ks + r0 * 64), 16, 0, 0);
    }
    __syncthreads();

    const int l15 = lane & 15, q = lane >> 4;
    const int tblk = (wave >> 1) * 64, sblk = (wave & 1) * 64;
    f32x4 acc[4][4];
    #pragma unroll
    for (int i = 0; i < 4; i++)
        #pragma unroll
        for (int j = 0; j < 4; j++) acc[i][j] = (f32x4)(0.f);

    #pragma unroll
    for (int ks = 0; ks < 2; ks++) {
        bf16x8 av[4], bv[4];
        #pragma unroll
        for (int mi = 0; mi < 4; mi++) {
            int r = tblk + mi * 16 + l15;
            av[mi] = *(const bf16x8*)&Qs[r * 64 + ((ks * 4 + q) ^ (r & 7)) * 8];
        }
        #pragma unroll
        for (int ni = 0; ni < 4; ni++) {
            int r = sblk + ni * 16 + l15;
            bv[ni] = *(const bf16x8*)&Ks[r * 64 + ((ks * 4 + q) ^ (r & 7)) * 8];
        }
        #pragma unroll
        for (int mi = 0; mi < 4; mi++)
            #pragma unroll
            for (int ni = 0; ni < 4; ni++)
                acc[mi][ni] = __builtin_amdgcn_mfma_f32_16x16x32_bf16(av[mi], bv[ni], acc[mi][ni], 0, 0, 0);
    }

    #pragma unroll
    for (int mi = 0; mi < 4; mi++) {
        #pragma unroll
        for (int ni = 0; ni < 4; ni++) {
            int scol = s0 + sblk + ni * 16 + l15;
            #pragma unroll
            for (int r = 0; r < 4; r++) {
                int t = t0 + tblk + mi * 16 + q * 4 + r;
                float v = acc[mi][ni][r] * 0.125f;
                v = fminf(fmaxf(v, -80.f), 80.f);
                attn[((size_t)bh * TT + t) * SS + scol] = v;
            }
        }
    }
}

// ---------------------------------------------------------------------------
// softmax + multiplicative tanh bias + renormalize (fp32, in-place on attn)
// ---------------------------------------------------------------------------
__global__ __launch_bounds__(256) void softmax_bias_kernel(
    const float* __restrict__ attn_bias, const float* __restrict__ bias_scale_p,
    float* __restrict__ attn)
{
    const int bid = blockIdx.x;
    const int t = bid & (TT - 1);
    const int tid = threadIdx.x;
    const int s0 = tid * 4;

    float* row = attn + (size_t)bid * SS;
    const float* brow = attn_bias + (size_t)bid * SS;

    __shared__ float red[256];

    float v0 = -INFINITY, v1 = -INFINITY, v2 = -INFINITY, v3 = -INFINITY;
    if (s0 <= t) {
        float4 rv = *(const float4*)&row[s0];
        v0 = rv.x;
        v1 = (s0 + 1 <= t) ? rv.y : -INFINITY;
        v2 = (s0 + 2 <= t) ? rv.z : -INFINITY;
        v3 = (s0 + 3 <= t) ? rv.w : -INFINITY;
    }
    float lmax = fmaxf(fmaxf(v0, v1), fmaxf(v2, v3));
    red[tid] = lmax;
    __syncthreads();
    for (int off = 128; off > 0; off >>= 1) {
        if (tid < off) red[tid] = fmaxf(red[tid], red[tid + off]);
        __syncthreads();
    }
    const float m = red[0];
    __syncthreads();

    float p0 = (v0 > -INFINITY) ? __expf(v0 - m) : 0.f;
    float p1 = (v1 > -INFINITY) ? __expf(v1 - m) : 0.f;
    float p2 = (v2 > -INFINITY) ? __expf(v2 - m) : 0.f;
    float p3 = (v3 > -INFINITY) ? __expf(v3 - m) : 0.f;
    red[tid] = p0 + p1 + p2 + p3;
    __syncthreads();
    for (int off = 128; off > 0; off >>= 1) {
        if (tid < off) red[tid] += red[tid + off];
        __syncthreads();
    }
    const float inv = 1.f / red[0];
    __syncthreads();

    const float bscale = bias_scale_p[0];
    float w0 = 0.f, w1 = 0.f, w2 = 0.f, w3 = 0.f;
    if (s0 <= t) {
        float4 bv = *(const float4*)&brow[s0];
        float e0 = __expf(-2.f * fabsf(bv.x));
        float e1 = __expf(-2.f * fabsf(bv.y));
        float e2 = __expf(-2.f * fabsf(bv.z));
        float e3 = __expf(-2.f * fabsf(bv.w));
        float t0 = copysignf((1.f - e0) / (1.f + e0), bv.x);
        float t1 = copysignf((1.f - e1) / (1.f + e1), bv.y);
        float t2 = copysignf((1.f - e2) / (1.f + e2), bv.z);
        float t3 = copysignf((1.f - e3) / (1.f + e3), bv.w);
        w0 = p0 * inv * fmaxf(1.f + bscale * t0, 1e-9f);
        w1 = p1 * inv * fmaxf(1.f + bscale * t1, 1e-9f);
        w2 = p2 * inv * fmaxf(1.f + bscale * t2, 1e-9f);
        w3 = p3 * inv * fmaxf(1.f + bscale * t3, 1e-9f);
    }
    red[tid] = w0 + w1 + w2 + w3;
    __syncthreads();
    for (int off = 128; off > 0; off >>= 1) {
        if (tid < off) red[tid] += red[tid + off];
        __syncthreads();
    }
    const float inv2 = 1.f / (red[0] + 1e-9f);

    float4 o;
    o.x = w0 * inv2; o.y = w1 * inv2; o.z = w2 * inv2; o.w = w3 * inv2;
    *(float4*)&row[s0] = o;
}

// ---------------------------------------------------------------------------
// AV: ao[b,t,h*64+dh] = sum_s attn[bh,t,s] * V[s,dh].  64t x 64dh per block.
// A staged fp32->bf16 manually; V staged from vT via global_load_lds.
// attn has exact zeros for s>t, so full diagonal tiles are safe.
// ---------------------------------------------------------------------------
__global__ __launch_bounds__(256) void av_mfma(
    const float* __restrict__ attn, const ushort_t* __restrict__ vT,
    ushort_t* __restrict__ ao)
{
    __shared__ ushort_t Asm[64 * 32];
    __shared__ ushort_t Vsm[64 * 32];

    const int tb = blockIdx.x;
    const int bh = blockIdx.y;
    const int b = bh >> 4, h = bh & 15;
    const int t0 = tb * 64;
    const int nsteps = (tb + 1) * 2;

    const int tid = threadIdx.x;
    const int wave = tid >> 6, lane = tid & 63;
    const int ar = tid >> 2, aq = tid & 3;
    const int aslot = aq ^ ((ar >> 1) & 3);
    const int vsr = lane >> 2;
    const int vgc = (lane & 3) ^ ((lane >> 3) & 3);
    const int l15 = lane & 15, q = lane >> 4;

    f32x4 acc[4];
    #pragma unroll
    for (int i = 0; i < 4; i++) acc[i] = (f32x4)(0.f);

    for (int st = 0; st < nsteps; st++) {
        const int s0 = st * 32;
        {   // stage A (fp32 -> bf16)
            const float* src = &attn[((size_t)bh * TT + t0 + ar) * SS + s0 + aq * 8];
            float4 u0 = *(const float4*)src;
            float4 u1 = *(const float4*)(src + 4);
            uint4 o;
            o.x = f2b(u0.x) | ((unsigned)f2b(u0.y) << 16);
            o.y = f2b(u0.z) | ((unsigned)f2b(u0.w) << 16);
            o.z = f2b(u1.x) | ((unsigned)f2b(u1.y) << 16);
            o.w = f2b(u1.z) | ((unsigned)f2b(u1.w) << 16);
            *(uint4*)&Asm[ar * 32 + aslot * 8] = o;
        }
        {   // stage V rows wave*16..+15
            int r0 = wave * 16;
            __builtin_amdgcn_global_load_lds(
                AS1(vT + ((size_t)bh * DH + r0 + vsr) * SS + s0 + vgc * 8),
                AS3(Vsm + r0 * 32), 16, 0, 0);
        }
        __syncthreads();

        bf16x8 a0, bv[4];
        {
            int r = wave * 16 + l15;
            a0 = *(const bf16x8*)&Asm[r * 32 + (q ^ ((r >> 1) & 3)) * 8];
        }
        #pragma unroll
        for (int ni = 0; ni < 4; ni++) {
            int r = ni * 16 + l15;
            bv[ni] = *(const bf16x8*)&Vsm[r * 32 + (q ^ ((r >> 1) & 3)) * 8];
        }
        #pragma unroll
        for (int ni = 0; ni < 4; ni++)
            acc[ni] = __builtin_amdgcn_mfma_f32_16x16x32_bf16(a0, bv[ni], acc[ni], 0, 0, 0);
        __syncthreads();
    }

    #pragma unroll
    for (int ni = 0; ni < 4; ni++) {
        int dh = ni * 16 + l15;
        #pragma unroll
        for (int r = 0; r < 4; r++) {
            int t = t0 + wave * 16 + q * 4 + r;
            ao[(size_t)(b * TT + t) * DD + h * DH + dh] = f2b(acc[ni][r]);
        }
    }
}

// ---------------------------------------------------------------------------
extern "C" void kernel_launch(void* const* d_in, const int* in_sizes, int n_in,
                              void* d_out, int out_size, void* d_ws, size_t ws_size,
                              hipStream_t stream)
{
    const float* q   = (const float*)d_in[0];
    const float* k   = (const float*)d_in[1];
    const float* v   = (const float*)d_in[2];
    const float* attn_bias = (const float*)d_in[4];
    const float* Wq = (const float*)d_in[5];
    const float* bq = (const float*)d_in[6];
    const float* Wk = (const float*)d_in[7];
    const float* bk = (const float*)d_in[8];
    const float* Wv = (const float*)d_in[9];
    const float* bv = (const float*)d_in[10];
    const float* Wo = (const float*)d_in[11];
    const float* bo = (const float*)d_in[12];
    const float* bscale = (const float*)d_in[13];

    // ws layout (32 MB total, with aliasing):
    char* base = (char*)d_ws;
    ushort_t* qb  = (ushort_t*)(base + (0ull << 20));   // 4 MB, later vT
    ushort_t* kb  = (ushort_t*)(base + (4ull << 20));   // 4 MB, later ao
    ushort_t* vb  = (ushort_t*)(base + (8ull << 20));   // 4 MB
    ushort_t* Wqb = (ushort_t*)(base + (12ull << 20));  // 2 MB
    ushort_t* Wkb = (ushort_t*)(base + (14ull << 20));  // 2 MB
    ushort_t* Wvb = (ushort_t*)(base + (16ull << 20));  // 2 MB
    ushort_t* Wob = (ushort_t*)(base + (18ull << 20));  // 2 MB
    ushort_t* qhb = (ushort_t*)(base + (20ull << 20));  // 4 MB
    ushort_t* khb = (ushort_t*)(base + (24ull << 20));  // 4 MB
    ushort_t* vhb = (ushort_t*)(base + (28ull << 20));  // 4 MB
    ushort_t* vT  = qb;   // alias: qb dead after proj_gemm
    ushort_t* aob = kb;   // alias: kb dead after proj_gemm

    float* out  = (float*)d_out;
    float* attn = out + (size_t)BB * TT * DD;

    cvt3_kernel<<<dim3(1024, 3), 256, 0, stream>>>(q, k, v, qb, kb, vb);
    cvt4_kernel<<<dim3(512, 4), 256, 0, stream>>>(Wq, Wk, Wv, Wo, Wqb, Wkb, Wvb, Wob);
    proj_gemm<<<dim3(8, 16, 3), 256, 0, stream>>>(qb, kb, vb, Wqb, Wkb, Wvb,
                                                  bq, bk, bv, qhb, khb, vhb);
    transpose_v<<<dim3(16, 32), 256, 0, stream>>>(vhb, vT);
    scores_mfma<<<dim3(36, 32), 256, 0, stream>>>(qhb, khb, attn);
    softmax_bias_kernel<<<dim3(BB * HH * TT), 256, 0, stream>>>(attn_bias, bscale, attn);
    av_mfma<<<dim3(16, 32), 256, 0, stream>>>(attn, vT, aob);
    oproj_gemm<<<dim3(8, 16), 256, 0, stream>>>(aob, Wob, bo, out);
}